// Round 6
// baseline (513.525 us; speedup 1.0000x reference)
//
#include <hip/hip_runtime.h>
#include <hip/hip_bf16.h>

typedef __attribute__((ext_vector_type(8))) short short8;
typedef __attribute__((ext_vector_type(4))) float f32x4;

static constexpr int DM = 1024;   // d_model
static constexpr int NH = 16;     // heads
static constexpr int DK = 64;     // head dim
static constexpr int SL = 2048;   // seq len
static constexpr int BB = 4;      // batch
static constexpr size_t QKV_ELEMS = (size_t)BB * NH * SL * DK;  // 8388608
static constexpr float NEG_BIG = -30000.0f;          // exp2 -> 0
static constexpr float SC_LOG2E = 0.125f * 1.44269504088896340736f; // /sqrt(64) * log2(e)

union PackB { __hip_bfloat16 h[8]; uint4 u; };

// ---------------------------------------------------------------------------
// GEMM: out = A (M x 1024) @ W^T  (W: 1024 x 1024 fp32 row-major).
// A is fp32 (A_BF16=false) or bf16 (A_BF16=true). Internal compute bf16 MFMA.
// MODE 0: bf16 scatter to [B,H,S,D]   (Q, K)
// MODE 1: bf16 scatter to [B,H,D,S]   (V transposed)
// MODE 2: fp32 row-major [M, 1024]    (final output)
// ---------------------------------------------------------------------------
template<bool A_BF16, int MODE>
__global__ __launch_bounds__(256)
void gemm_bt(const void* __restrict__ Ap,
             const float* __restrict__ W,
             void* __restrict__ outp)
{
    __shared__ __hip_bfloat16 As[128][40];   // +8 pad
    __shared__ __hip_bfloat16 Bs[128][40];
    const int tid  = threadIdx.x;
    const int m0   = blockIdx.x * 128;
    const int n0   = blockIdx.y * 128;
    const int w    = tid >> 6;
    const int lane = tid & 63;
    const int quad = lane >> 4;
    const int ln   = lane & 15;
    const int wm   = (w & 1) * 64;
    const int wn   = (w >> 1) * 64;
    const int lr   = tid >> 1;          // staging row 0..127
    const int lc   = (tid & 1) * 16;    // staging col 0 / 16

    f32x4 acc[4][4] = {};

    for (int k0 = 0; k0 < DM; k0 += 32) {
        if (A_BF16) {
            const uint4* ap = reinterpret_cast<const uint4*>(
                (const __hip_bfloat16*)Ap + (size_t)(m0 + lr) * DM + k0 + lc);
            uint4 a0 = ap[0], a1 = ap[1];
            *reinterpret_cast<uint4*>(&As[lr][lc])     = a0;
            *reinterpret_cast<uint4*>(&As[lr][lc + 8]) = a1;
        } else {
            const float4* ap = reinterpret_cast<const float4*>(
                (const float*)Ap + (size_t)(m0 + lr) * DM + k0 + lc);
            float4 f0 = ap[0], f1 = ap[1], f2 = ap[2], f3 = ap[3];
            PackB p0, p1;
            p0.h[0] = __float2bfloat16(f0.x); p0.h[1] = __float2bfloat16(f0.y);
            p0.h[2] = __float2bfloat16(f0.z); p0.h[3] = __float2bfloat16(f0.w);
            p0.h[4] = __float2bfloat16(f1.x); p0.h[5] = __float2bfloat16(f1.y);
            p0.h[6] = __float2bfloat16(f1.z); p0.h[7] = __float2bfloat16(f1.w);
            p1.h[0] = __float2bfloat16(f2.x); p1.h[1] = __float2bfloat16(f2.y);
            p1.h[2] = __float2bfloat16(f2.z); p1.h[3] = __float2bfloat16(f2.w);
            p1.h[4] = __float2bfloat16(f3.x); p1.h[5] = __float2bfloat16(f3.y);
            p1.h[6] = __float2bfloat16(f3.z); p1.h[7] = __float2bfloat16(f3.w);
            *reinterpret_cast<uint4*>(&As[lr][lc])     = p0.u;
            *reinterpret_cast<uint4*>(&As[lr][lc + 8]) = p1.u;
        }
        {
            const float4* wp = reinterpret_cast<const float4*>(
                W + (size_t)(n0 + lr) * DM + k0 + lc);
            float4 f0 = wp[0], f1 = wp[1], f2 = wp[2], f3 = wp[3];
            PackB p0, p1;
            p0.h[0] = __float2bfloat16(f0.x); p0.h[1] = __float2bfloat16(f0.y);
            p0.h[2] = __float2bfloat16(f0.z); p0.h[3] = __float2bfloat16(f0.w);
            p0.h[4] = __float2bfloat16(f1.x); p0.h[5] = __float2bfloat16(f1.y);
            p0.h[6] = __float2bfloat16(f1.z); p0.h[7] = __float2bfloat16(f1.w);
            p1.h[0] = __float2bfloat16(f2.x); p1.h[1] = __float2bfloat16(f2.y);
            p1.h[2] = __float2bfloat16(f2.z); p1.h[3] = __float2bfloat16(f2.w);
            p1.h[4] = __float2bfloat16(f3.x); p1.h[5] = __float2bfloat16(f3.y);
            p1.h[6] = __float2bfloat16(f3.z); p1.h[7] = __float2bfloat16(f3.w);
            *reinterpret_cast<uint4*>(&Bs[lr][lc])     = p0.u;
            *reinterpret_cast<uint4*>(&Bs[lr][lc + 8]) = p1.u;
        }
        __syncthreads();

        short8 a[4], b[4];
        #pragma unroll
        for (int i = 0; i < 4; i++)
            a[i] = *reinterpret_cast<const short8*>(&As[wm + i*16 + ln][quad*8]);
        #pragma unroll
        for (int j = 0; j < 4; j++)
            b[j] = *reinterpret_cast<const short8*>(&Bs[wn + j*16 + ln][quad*8]);
        #pragma unroll
        for (int i = 0; i < 4; i++)
            #pragma unroll
            for (int j = 0; j < 4; j++)
                acc[i][j] = __builtin_amdgcn_mfma_f32_16x16x32_bf16(a[i], b[j], acc[i][j], 0, 0, 0);
        __syncthreads();
    }

    // Epilogue: C/D layout col=lane&15, row=quad*4+reg  [m89/m91]
    #pragma unroll
    for (int i = 0; i < 4; i++) {
        #pragma unroll
        for (int j = 0; j < 4; j++) {
            #pragma unroll
            for (int r = 0; r < 4; r++) {
                const int m = m0 + wm + i*16 + quad*4 + r;
                const int n = n0 + wn + j*16 + ln;
                const float v = acc[i][j][r];
                if (MODE == 2) {
                    ((float*)outp)[(size_t)m * DM + n] = v;
                } else {
                    const int b_ = m >> 11;
                    const int s  = m & 2047;
                    const int h  = n >> 6;
                    const int d  = n & 63;
                    size_t idx;
                    if (MODE == 0) idx = ((size_t)((b_*NH + h)*SL + s))*DK + d;
                    else           idx = ((size_t)((b_*NH + h)*DK + d))*SL + s;
                    ((__hip_bfloat16*)outp)[idx] = __float2bfloat16(v);
                }
            }
        }
    }
}

// ---------------------------------------------------------------------------
// Causal flash attention, barrier-free, K-prefetch software pipeline.
// Q, K: [BH, S, DK];  Vt: [BH, DK, S];  O: [B, S, H, DK]  (all bf16)
// Grid (16, 64): block bx handles q-tiles bx and 31-bx -> 33 k-tiles.
// Load-issue order per iter: V(cur) FIRST (oldest), then K(next) — so the
// compiler's waitcnt before PV is vmcnt(8) (V done, K-next in flight) and
// QK^T waits only on K issued a full iteration earlier (already complete).
// ---------------------------------------------------------------------------
__global__ __launch_bounds__(256, 4)
void attn_causal(const __hip_bfloat16* __restrict__ Q,
                 const __hip_bfloat16* __restrict__ K,
                 const __hip_bfloat16* __restrict__ Vt,
                 __hip_bfloat16* __restrict__ O)
{
    __shared__ __hip_bfloat16 p_lds[4][16][72];   // per-wave P slab, padded

    const int tid  = threadIdx.x;
    const int w    = tid >> 6;
    const int lane = tid & 63;
    const int quad = lane >> 4;
    const int ln   = lane & 15;
    const int bh   = blockIdx.y;         // b*NH + h
    const int b_   = bh >> 4;
    const int h    = bh & 15;

    const __hip_bfloat16* Qb = Q  + (size_t)bh * SL * DK;
    const __hip_bfloat16* Kb = K  + (size_t)bh * SL * DK;
    const __hip_bfloat16* Vb = Vt + (size_t)bh * DK * SL;

    for (int pass = 0; pass < 2; ++pass) {
        const int qt    = (pass == 0) ? (int)blockIdx.x : 31 - (int)blockIdx.x;
        const int q0    = qt * 64;
        const int qbase = q0 + w * 16;

        short8 aq0 = *reinterpret_cast<const short8*>(Qb + (size_t)(qbase + ln) * DK + quad*8);
        short8 aq1 = *reinterpret_cast<const short8*>(Qb + (size_t)(qbase + ln) * DK + 32 + quad*8);

        f32x4 acc[4] = {};
        float lsum[4] = {0.f, 0.f, 0.f, 0.f};

        // preload K fragments for k0 = 0
        short8 kcur0[4], kcur1[4];
        #pragma unroll
        for (int kc = 0; kc < 4; kc++) {
            const __hip_bfloat16* kr = Kb + (size_t)(kc*16 + ln) * DK + quad*8;
            kcur0[kc] = *reinterpret_cast<const short8*>(kr);
            kcur1[kc] = *reinterpret_cast<const short8*>(kr + 32);
        }

        for (int k0 = 0; k0 <= q0; k0 += 64) {
            // (1) V(cur) loads — issued FIRST (become the oldest vmem ops)
            short8 bv0[4], bv1[4];
            #pragma unroll
            for (int nt = 0; nt < 4; nt++) {
                const __hip_bfloat16* vr = Vb + (size_t)(nt*16 + ln) * SL + k0 + quad*8;
                bv0[nt] = *reinterpret_cast<const short8*>(vr);
                bv1[nt] = *reinterpret_cast<const short8*>(vr + 32);
            }
            // (2) K(next) prefetch (clamped in-bounds; unused on last iter)
            const int k0n = (k0 + 64 <= q0) ? (k0 + 64) : q0;
            short8 knxt0[4], knxt1[4];
            #pragma unroll
            for (int kc = 0; kc < 4; kc++) {
                const __hip_bfloat16* kr = Kb + (size_t)(k0n + kc*16 + ln) * DK + quad*8;
                knxt0[kc] = *reinterpret_cast<const short8*>(kr);
                knxt1[kc] = *reinterpret_cast<const short8*>(kr + 32);
            }
            // (3) QK^T with current K (prefetched last iteration)
            f32x4 s[4];
            #pragma unroll
            for (int kc = 0; kc < 4; kc++) {
                f32x4 z = {};
                z = __builtin_amdgcn_mfma_f32_16x16x32_bf16(aq0, kcur0[kc], z, 0, 0, 0);
                z = __builtin_amdgcn_mfma_f32_16x16x32_bf16(aq1, kcur1[kc], z, 0, 0, 0);
                s[kc] = z;
            }
            // (4) softmax numerator, P -> per-wave LDS slab
            const bool diag = (k0 == q0);   // only diagonal tile needs masking
            #pragma unroll
            for (int kc = 0; kc < 4; kc++) {
                #pragma unroll
                for (int r = 0; r < 4; r++) {
                    float v = s[kc][r] * SC_LOG2E;
                    if (diag) {
                        const int kg = k0 + kc*16 + ln;
                        const int qg = qbase + quad*4 + r;
                        if (kg > qg) v = NEG_BIG;
                    }
                    const float p = __builtin_amdgcn_exp2f(v);
                    lsum[r] += p;
                    p_lds[w][quad*4 + r][kc*16 + ln] = __float2bfloat16(p);
                }
            }
            // (5) P as A-fragments (intra-wave LDS, no barrier) + PV
            short8 ap0 = *reinterpret_cast<const short8*>(&p_lds[w][ln][quad*8]);
            short8 ap1 = *reinterpret_cast<const short8*>(&p_lds[w][ln][32 + quad*8]);
            #pragma unroll
            for (int nt = 0; nt < 4; nt++) {
                acc[nt] = __builtin_amdgcn_mfma_f32_16x16x32_bf16(ap0, bv0[nt], acc[nt], 0, 0, 0);
                acc[nt] = __builtin_amdgcn_mfma_f32_16x16x32_bf16(ap1, bv1[nt], acc[nt], 0, 0, 0);
            }
            // (6) rotate prefetch registers
            #pragma unroll
            for (int kc = 0; kc < 4; kc++) { kcur0[kc] = knxt0[kc]; kcur1[kc] = knxt1[kc]; }
        }

        // single final reduction of l over the quad's 16 lanes
        #pragma unroll
        for (int r = 0; r < 4; r++) {
            float v = lsum[r];
            v += __shfl_xor(v, 1, 64);
            v += __shfl_xor(v, 2, 64);
            v += __shfl_xor(v, 4, 64);
            v += __shfl_xor(v, 8, 64);
            lsum[r] = v;
        }

        #pragma unroll
        for (int nt = 0; nt < 4; nt++) {
            #pragma unroll
            for (int r = 0; r < 4; r++) {
                const int sI = qbase + quad*4 + r;
                const int d  = nt*16 + ln;
                const float v = acc[nt][r] / lsum[r];
                O[(((size_t)b_ * SL + sI) * NH + h) * DK + d] = __float2bfloat16(v);
            }
        }
    }
}

// ---------------------------------------------------------------------------
extern "C" void kernel_launch(void* const* d_in, const int* in_sizes, int n_in,
                              void* d_out, int out_size, void* d_ws, size_t ws_size,
                              hipStream_t stream)
{
    const float* x  = (const float*)d_in[0];
    const float* Wq = (const float*)d_in[1];
    const float* Wk = (const float*)d_in[2];
    const float* Wv = (const float*)d_in[3];
    const float* Wo = (const float*)d_in[4];

    __hip_bfloat16* q_ws = (__hip_bfloat16*)d_ws;
    __hip_bfloat16* k_ws = q_ws + QKV_ELEMS;
    __hip_bfloat16* v_ws = k_ws + QKV_ELEMS;          // [B,H,D,S]
    __hip_bfloat16* obuf = (__hip_bfloat16*)d_out;    // O bf16 in d_out's first half
    float*          fbuf = (float*)d_ws;              // fp32 result over dead Q+K

    const dim3 gg(64, 8), gb(256);
    gemm_bt<false, 0><<<gg, gb, 0, stream>>>(x, Wq, q_ws);
    gemm_bt<false, 0><<<gg, gb, 0, stream>>>(x, Wk, k_ws);
    gemm_bt<false, 1><<<gg, gb, 0, stream>>>(x, Wv, v_ws);

    attn_causal<<<dim3(16, BB*NH), 256, 0, stream>>>(q_ws, k_ws, v_ws, obuf);

    gemm_bt<true, 2><<<gg, gb, 0, stream>>>(obuf, Wo, fbuf);

    (void)hipMemcpyAsync(d_out, fbuf, QKV_ELEMS * sizeof(float),
                         hipMemcpyDeviceToDevice, stream);
}

// Round 7
// 354.079 us; speedup vs baseline: 1.4503x; 1.4503x over previous
//
#include <hip/hip_runtime.h>
#include <hip/hip_bf16.h>

typedef __attribute__((ext_vector_type(8))) short short8;
typedef __attribute__((ext_vector_type(4))) float f32x4;

static constexpr int DM = 1024;   // d_model
static constexpr int NH = 16;     // heads
static constexpr int DK = 64;     // head dim
static constexpr int SL = 2048;   // seq len
static constexpr int BB = 4;      // batch
static constexpr size_t QKV_ELEMS = (size_t)BB * NH * SL * DK;  // 8388608
static constexpr float NEG_BIG = -30000.0f;          // exp2 -> 0
static constexpr float SC_LOG2E = 0.125f * 1.44269504088896340736f; // /sqrt(64) * log2(e)

union PackB { __hip_bfloat16 h[8]; uint4 u; };

// ---------------------------------------------------------------------------
// GEMM: out = A (M x 1024) @ W^T  (W: 1024 x 1024 fp32 row-major).
// A is fp32 (A_BF16=false) or bf16 (A_BF16=true). Internal compute bf16 MFMA.
// MODE 0: bf16 scatter to [B,H,S,D]   (Q, K)
// MODE 1: bf16 scatter to [B,H,D,S]   (V transposed)
// MODE 2: fp32 row-major [M, 1024]    (final output)
// ---------------------------------------------------------------------------
template<bool A_BF16, int MODE>
__global__ __launch_bounds__(256)
void gemm_bt(const void* __restrict__ Ap,
             const float* __restrict__ W,
             void* __restrict__ outp)
{
    __shared__ __hip_bfloat16 As[128][40];   // +8 pad
    __shared__ __hip_bfloat16 Bs[128][40];
    const int tid  = threadIdx.x;
    const int m0   = blockIdx.x * 128;
    const int n0   = blockIdx.y * 128;
    const int w    = tid >> 6;
    const int lane = tid & 63;
    const int quad = lane >> 4;
    const int ln   = lane & 15;
    const int wm   = (w & 1) * 64;
    const int wn   = (w >> 1) * 64;
    const int lr   = tid >> 1;          // staging row 0..127
    const int lc   = (tid & 1) * 16;    // staging col 0 / 16

    f32x4 acc[4][4] = {};

    for (int k0 = 0; k0 < DM; k0 += 32) {
        if (A_BF16) {
            const uint4* ap = reinterpret_cast<const uint4*>(
                (const __hip_bfloat16*)Ap + (size_t)(m0 + lr) * DM + k0 + lc);
            uint4 a0 = ap[0], a1 = ap[1];
            *reinterpret_cast<uint4*>(&As[lr][lc])     = a0;
            *reinterpret_cast<uint4*>(&As[lr][lc + 8]) = a1;
        } else {
            const float4* ap = reinterpret_cast<const float4*>(
                (const float*)Ap + (size_t)(m0 + lr) * DM + k0 + lc);
            float4 f0 = ap[0], f1 = ap[1], f2 = ap[2], f3 = ap[3];
            PackB p0, p1;
            p0.h[0] = __float2bfloat16(f0.x); p0.h[1] = __float2bfloat16(f0.y);
            p0.h[2] = __float2bfloat16(f0.z); p0.h[3] = __float2bfloat16(f0.w);
            p0.h[4] = __float2bfloat16(f1.x); p0.h[5] = __float2bfloat16(f1.y);
            p0.h[6] = __float2bfloat16(f1.z); p0.h[7] = __float2bfloat16(f1.w);
            p1.h[0] = __float2bfloat16(f2.x); p1.h[1] = __float2bfloat16(f2.y);
            p1.h[2] = __float2bfloat16(f2.z); p1.h[3] = __float2bfloat16(f2.w);
            p1.h[4] = __float2bfloat16(f3.x); p1.h[5] = __float2bfloat16(f3.y);
            p1.h[6] = __float2bfloat16(f3.z); p1.h[7] = __float2bfloat16(f3.w);
            *reinterpret_cast<uint4*>(&As[lr][lc])     = p0.u;
            *reinterpret_cast<uint4*>(&As[lr][lc + 8]) = p1.u;
        }
        {
            const float4* wp = reinterpret_cast<const float4*>(
                W + (size_t)(n0 + lr) * DM + k0 + lc);
            float4 f0 = wp[0], f1 = wp[1], f2 = wp[2], f3 = wp[3];
            PackB p0, p1;
            p0.h[0] = __float2bfloat16(f0.x); p0.h[1] = __float2bfloat16(f0.y);
            p0.h[2] = __float2bfloat16(f0.z); p0.h[3] = __float2bfloat16(f0.w);
            p0.h[4] = __float2bfloat16(f1.x); p0.h[5] = __float2bfloat16(f1.y);
            p0.h[6] = __float2bfloat16(f1.z); p0.h[7] = __float2bfloat16(f1.w);
            p1.h[0] = __float2bfloat16(f2.x); p1.h[1] = __float2bfloat16(f2.y);
            p1.h[2] = __float2bfloat16(f2.z); p1.h[3] = __float2bfloat16(f2.w);
            p1.h[4] = __float2bfloat16(f3.x); p1.h[5] = __float2bfloat16(f3.y);
            p1.h[6] = __float2bfloat16(f3.z); p1.h[7] = __float2bfloat16(f3.w);
            *reinterpret_cast<uint4*>(&Bs[lr][lc])     = p0.u;
            *reinterpret_cast<uint4*>(&Bs[lr][lc + 8]) = p1.u;
        }
        __syncthreads();

        short8 a[4], b[4];
        #pragma unroll
        for (int i = 0; i < 4; i++)
            a[i] = *reinterpret_cast<const short8*>(&As[wm + i*16 + ln][quad*8]);
        #pragma unroll
        for (int j = 0; j < 4; j++)
            b[j] = *reinterpret_cast<const short8*>(&Bs[wn + j*16 + ln][quad*8]);
        #pragma unroll
        for (int i = 0; i < 4; i++)
            #pragma unroll
            for (int j = 0; j < 4; j++)
                acc[i][j] = __builtin_amdgcn_mfma_f32_16x16x32_bf16(a[i], b[j], acc[i][j], 0, 0, 0);
        __syncthreads();
    }

    // Epilogue: C/D layout col=lane&15, row=quad*4+reg  [m89/m91]
    #pragma unroll
    for (int i = 0; i < 4; i++) {
        #pragma unroll
        for (int j = 0; j < 4; j++) {
            #pragma unroll
            for (int r = 0; r < 4; r++) {
                const int m = m0 + wm + i*16 + quad*4 + r;
                const int n = n0 + wn + j*16 + ln;
                const float v = acc[i][j][r];
                if (MODE == 2) {
                    ((float*)outp)[(size_t)m * DM + n] = v;
                } else {
                    const int b_ = m >> 11;
                    const int s  = m & 2047;
                    const int h  = n >> 6;
                    const int d  = n & 63;
                    size_t idx;
                    if (MODE == 0) idx = ((size_t)((b_*NH + h)*SL + s))*DK + d;
                    else           idx = ((size_t)((b_*NH + h)*DK + d))*SL + s;
                    ((__hip_bfloat16*)outp)[idx] = __float2bfloat16(v);
                }
            }
        }
    }
}

// ---------------------------------------------------------------------------
// Causal flash attention, LDS-staged K/V tiles (m97 2-barrier structure).
// Q, K: [BH, S, DK];  Vt: [BH, DK, S];  O: [B, S, H, DK]  (all bf16)
// Grid (16, 64): block bx handles q-tiles bx and 31-bx -> 33 k-tiles
// (perfect balance). 4 waves x 16 q-rows. K/V tiles staged once per block
// into padded LDS (shared by all 4 waves; was 4x redundant global loads).
// Trip count is block-uniform -> barriers convergent.
// ---------------------------------------------------------------------------
__global__ __launch_bounds__(256)
void attn_causal(const __hip_bfloat16* __restrict__ Q,
                 const __hip_bfloat16* __restrict__ K,
                 const __hip_bfloat16* __restrict__ Vt,
                 __hip_bfloat16* __restrict__ O)
{
    __shared__ __hip_bfloat16 Ks[64][72];        // [key][d]   +8 pad
    __shared__ __hip_bfloat16 Vs[64][72];        // [d][key]   +8 pad
    __shared__ __hip_bfloat16 p_lds[4][16][72];  // per-wave P slab

    const int tid  = threadIdx.x;
    const int w    = tid >> 6;
    const int lane = tid & 63;
    const int quad = lane >> 4;
    const int ln   = lane & 15;
    const int bh   = blockIdx.y;         // b*NH + h
    const int b_   = bh >> 4;
    const int h    = bh & 15;

    // staging coords: 256 threads cover 32 rows x 8 chunks (16 B) per round
    const int srow   = tid >> 3;         // 0..31
    const int schunk = (tid & 7) * 8;    // element offset 0,8,...,56

    const __hip_bfloat16* Qb = Q  + (size_t)bh * SL * DK;
    const __hip_bfloat16* Kb = K  + (size_t)bh * SL * DK;
    const __hip_bfloat16* Vb = Vt + (size_t)bh * DK * SL;

    for (int pass = 0; pass < 2; ++pass) {
        const int qt    = (pass == 0) ? (int)blockIdx.x : 31 - (int)blockIdx.x;
        const int q0    = qt * 64;
        const int qbase = q0 + w * 16;

        short8 aq0 = *reinterpret_cast<const short8*>(Qb + (size_t)(qbase + ln) * DK + quad*8);
        short8 aq1 = *reinterpret_cast<const short8*>(Qb + (size_t)(qbase + ln) * DK + 32 + quad*8);

        f32x4 acc[4] = {};
        float lsum[4] = {0.f, 0.f, 0.f, 0.f};

        for (int k0 = 0; k0 <= q0; k0 += 64) {
            // ---- stage K tile [64 keys][64 d] and V tile [64 d][64 keys] ----
            const __hip_bfloat16* Kg = Kb + (size_t)(k0 + srow) * DK + schunk;
            uint4 kv0 = *reinterpret_cast<const uint4*>(Kg);
            uint4 kv1 = *reinterpret_cast<const uint4*>(Kg + 32 * DK);
            const __hip_bfloat16* Vg = Vb + (size_t)srow * SL + k0 + schunk;
            uint4 vv0 = *reinterpret_cast<const uint4*>(Vg);
            uint4 vv1 = *reinterpret_cast<const uint4*>(Vg + 32 * SL);
            __syncthreads();   // prior iteration's LDS reads complete
            *reinterpret_cast<uint4*>(&Ks[srow     ][schunk]) = kv0;
            *reinterpret_cast<uint4*>(&Ks[srow + 32][schunk]) = kv1;
            *reinterpret_cast<uint4*>(&Vs[srow     ][schunk]) = vv0;
            *reinterpret_cast<uint4*>(&Vs[srow + 32][schunk]) = vv1;
            __syncthreads();   // staging visible to all waves

            // ---- QK^T from LDS ----
            f32x4 s[4];
            #pragma unroll
            for (int kc = 0; kc < 4; kc++) {
                short8 bk0 = *reinterpret_cast<const short8*>(&Ks[kc*16 + ln][quad*8]);
                short8 bk1 = *reinterpret_cast<const short8*>(&Ks[kc*16 + ln][32 + quad*8]);
                f32x4 z = {};
                z = __builtin_amdgcn_mfma_f32_16x16x32_bf16(aq0, bk0, z, 0, 0, 0);
                z = __builtin_amdgcn_mfma_f32_16x16x32_bf16(aq1, bk1, z, 0, 0, 0);
                s[kc] = z;
            }
            // ---- softmax numerator, P -> per-wave LDS slab ----
            const bool diag = (k0 == q0);   // only diagonal tile needs masking
            #pragma unroll
            for (int kc = 0; kc < 4; kc++) {
                #pragma unroll
                for (int r = 0; r < 4; r++) {
                    float v = s[kc][r] * SC_LOG2E;
                    if (diag) {
                        const int kg = k0 + kc*16 + ln;
                        const int qg = qbase + quad*4 + r;
                        if (kg > qg) v = NEG_BIG;
                    }
                    const float p = __builtin_amdgcn_exp2f(v);
                    lsum[r] += p;
                    p_lds[w][quad*4 + r][kc*16 + ln] = __float2bfloat16(p);
                }
            }
            // ---- PV: P as A-fragments (intra-wave LDS), V from shared tile ----
            short8 ap0 = *reinterpret_cast<const short8*>(&p_lds[w][ln][quad*8]);
            short8 ap1 = *reinterpret_cast<const short8*>(&p_lds[w][ln][32 + quad*8]);
            #pragma unroll
            for (int nt = 0; nt < 4; nt++) {
                short8 bv0 = *reinterpret_cast<const short8*>(&Vs[nt*16 + ln][quad*8]);
                short8 bv1 = *reinterpret_cast<const short8*>(&Vs[nt*16 + ln][32 + quad*8]);
                acc[nt] = __builtin_amdgcn_mfma_f32_16x16x32_bf16(ap0, bv0, acc[nt], 0, 0, 0);
                acc[nt] = __builtin_amdgcn_mfma_f32_16x16x32_bf16(ap1, bv1, acc[nt], 0, 0, 0);
            }
        }

        // single final reduction of l over the quad's 16 lanes
        #pragma unroll
        for (int r = 0; r < 4; r++) {
            float v = lsum[r];
            v += __shfl_xor(v, 1, 64);
            v += __shfl_xor(v, 2, 64);
            v += __shfl_xor(v, 4, 64);
            v += __shfl_xor(v, 8, 64);
            lsum[r] = v;
        }

        #pragma unroll
        for (int nt = 0; nt < 4; nt++) {
            #pragma unroll
            for (int r = 0; r < 4; r++) {
                const int sI = qbase + quad*4 + r;
                const int d  = nt*16 + ln;
                const float v = acc[nt][r] / lsum[r];
                O[(((size_t)b_ * SL + sI) * NH + h) * DK + d] = __float2bfloat16(v);
            }
        }
    }
}

// ---------------------------------------------------------------------------
extern "C" void kernel_launch(void* const* d_in, const int* in_sizes, int n_in,
                              void* d_out, int out_size, void* d_ws, size_t ws_size,
                              hipStream_t stream)
{
    const float* x  = (const float*)d_in[0];
    const float* Wq = (const float*)d_in[1];
    const float* Wk = (const float*)d_in[2];
    const float* Wv = (const float*)d_in[3];
    const float* Wo = (const float*)d_in[4];

    __hip_bfloat16* q_ws = (__hip_bfloat16*)d_ws;
    __hip_bfloat16* k_ws = q_ws + QKV_ELEMS;
    __hip_bfloat16* v_ws = k_ws + QKV_ELEMS;          // [B,H,D,S]
    __hip_bfloat16* obuf = (__hip_bfloat16*)d_out;    // O bf16 in d_out's first half
    float*          fbuf = (float*)d_ws;              // fp32 result over dead Q+K

    const dim3 gg(64, 8), gb(256);
    gemm_bt<false, 0><<<gg, gb, 0, stream>>>(x, Wq, q_ws);
    gemm_bt<false, 0><<<gg, gb, 0, stream>>>(x, Wk, k_ws);
    gemm_bt<false, 1><<<gg, gb, 0, stream>>>(x, Wv, v_ws);

    attn_causal<<<dim3(16, BB*NH), 256, 0, stream>>>(q_ws, k_ws, v_ws, obuf);

    gemm_bt<true, 2><<<gg, gb, 0, stream>>>(obuf, Wo, fbuf);

    (void)hipMemcpyAsync(d_out, fbuf, QKV_ELEMS * sizeof(float),
                         hipMemcpyDeviceToDevice, stream);
}

// Round 8
// 291.301 us; speedup vs baseline: 1.7629x; 1.2155x over previous
//
#include <hip/hip_runtime.h>
#include <hip/hip_bf16.h>

typedef __attribute__((ext_vector_type(8))) short short8;
typedef __attribute__((ext_vector_type(4))) float f32x4;

static constexpr int DM = 1024;   // d_model
static constexpr int NH = 16;     // heads
static constexpr int DK = 64;     // head dim
static constexpr int SL = 2048;   // seq len
static constexpr int BB = 4;      // batch
static constexpr size_t QKV_ELEMS = (size_t)BB * NH * SL * DK;  // 8388608
static constexpr float NEG_BIG = -30000.0f;          // exp2 -> 0
static constexpr float SC_LOG2E = 0.125f * 1.44269504088896340736f; // /sqrt(64)*log2(e)

union PackB { __hip_bfloat16 h[8]; uint4 u; };
union Pack4 { __hip_bfloat16 h[4]; uint2 u; };

// async global->LDS, 16 B per lane (dest = wave-uniform base + lane*16)
typedef __attribute__((address_space(1))) unsigned int gu32;
typedef __attribute__((address_space(3))) unsigned int lu32;
__device__ __forceinline__ void async_copy16(const void* g, void* l) {
    __builtin_amdgcn_global_load_lds((gu32*)g, (lu32*)l, 16, 0, 0);
}

// ---------------------------------------------------------------------------
// Bulk fp32 -> bf16 convert: x (8M elems) then Wq,Wk,Wv,Wo (1M each) into one
// contiguous bf16 region. One float4 per thread.
// ---------------------------------------------------------------------------
__global__ __launch_bounds__(256)
void cvt_all(const float* __restrict__ x,
             const float* __restrict__ wq, const float* __restrict__ wk,
             const float* __restrict__ wv, const float* __restrict__ wo,
             __hip_bfloat16* __restrict__ dst)
{
    const size_t i = (size_t)blockIdx.x * 256 + threadIdx.x;  // float4 index
    const float* src; size_t local;
    if (i < 2097152) { src = x; local = i; }
    else {
        const size_t j = i - 2097152;
        const int r = (int)(j >> 18);           // 262144 float4 per W
        local = j & 262143;
        src = (r == 0) ? wq : (r == 1) ? wk : (r == 2) ? wv : wo;
    }
    float4 f = reinterpret_cast<const float4*>(src)[local];
    Pack4 p;
    p.h[0] = __float2bfloat16(f.x); p.h[1] = __float2bfloat16(f.y);
    p.h[2] = __float2bfloat16(f.z); p.h[3] = __float2bfloat16(f.w);
    reinterpret_cast<uint2*>(dst)[i] = p.u;
}

// ---------------------------------------------------------------------------
// Pure-bf16 GEMM, m97 structure: out = A (M x 1024 bf16) @ W^T (1024x1024 bf16)
// global_load_lds width=16 staging into contiguous (unpadded) LDS tiles.
// MODE 0: bf16 scatter [B,H,S,D]; MODE 1: bf16 scatter [B,H,D,S];
// MODE 2: fp32 row-major [M,1024].
// ---------------------------------------------------------------------------
template<int MODE>
__global__ __launch_bounds__(256)
void gemm_lds(const __hip_bfloat16* __restrict__ A,
              const __hip_bfloat16* __restrict__ W,
              void* __restrict__ outp)
{
    __shared__ __hip_bfloat16 As[128 * 32];   // contiguous: global_load_lds order
    __shared__ __hip_bfloat16 Bs[128 * 32];
    const int tid  = threadIdx.x;
    const int m0   = blockIdx.x * 128;
    const int n0   = blockIdx.y * 128;
    const int w    = tid >> 6;
    const int lane = tid & 63;
    const int quad = lane >> 4;
    const int ln   = lane & 15;
    const int wm   = (w & 1) * 64;
    const int wn   = (w >> 1) * 64;

    // staging: wave w covers rows [w*32, w*32+32), 2 instrs of 16 rows each.
    // lane l -> row l>>2, 16B chunk l&3 (LDS dest = base + l*16, matches).
    const int srow   = lane >> 2;        // 0..15
    const int schunk = (lane & 3) * 8;   // element offset

    f32x4 acc[4][4] = {};

    for (int k0 = 0; k0 < DM; k0 += 32) {
        #pragma unroll
        for (int j = 0; j < 2; j++) {
            const int rbase = w * 32 + j * 16;
            async_copy16(A + (size_t)(m0 + rbase + srow) * DM + k0 + schunk,
                         &As[rbase * 32]);
            async_copy16(W + (size_t)(n0 + rbase + srow) * DM + k0 + schunk,
                         &Bs[rbase * 32]);
        }
        __syncthreads();

        short8 a[4], b[4];
        #pragma unroll
        for (int i = 0; i < 4; i++)
            a[i] = *reinterpret_cast<const short8*>(&As[(wm + i*16 + ln) * 32 + quad*8]);
        #pragma unroll
        for (int j = 0; j < 4; j++)
            b[j] = *reinterpret_cast<const short8*>(&Bs[(wn + j*16 + ln) * 32 + quad*8]);
        #pragma unroll
        for (int i = 0; i < 4; i++)
            #pragma unroll
            for (int j = 0; j < 4; j++)
                acc[i][j] = __builtin_amdgcn_mfma_f32_16x16x32_bf16(a[i], b[j], acc[i][j], 0, 0, 0);
        __syncthreads();
    }

    // Epilogue: C/D layout col=lane&15, row=quad*4+reg  [m89/m91]
    #pragma unroll
    for (int i = 0; i < 4; i++) {
        #pragma unroll
        for (int j = 0; j < 4; j++) {
            #pragma unroll
            for (int r = 0; r < 4; r++) {
                const int m = m0 + wm + i*16 + quad*4 + r;
                const int n = n0 + wn + j*16 + ln;
                const float v = acc[i][j][r];
                if (MODE == 2) {
                    ((float*)outp)[(size_t)m * DM + n] = v;
                } else {
                    const int b_ = m >> 11;
                    const int s  = m & 2047;
                    const int h  = n >> 6;
                    const int d  = n & 63;
                    size_t idx;
                    if (MODE == 0) idx = ((size_t)((b_*NH + h)*SL + s))*DK + d;
                    else           idx = ((size_t)((b_*NH + h)*DK + d))*SL + s;
                    ((__hip_bfloat16*)outp)[idx] = __float2bfloat16(v);
                }
            }
        }
    }
}

// ---------------------------------------------------------------------------
// Fallback GEMM (round-7 proven): fp32 inputs, convert during staging.
// ---------------------------------------------------------------------------
template<bool A_BF16, int MODE>
__global__ __launch_bounds__(256)
void gemm_bt(const void* __restrict__ Ap,
             const float* __restrict__ W,
             void* __restrict__ outp)
{
    __shared__ __hip_bfloat16 As[128][40];
    __shared__ __hip_bfloat16 Bs[128][40];
    const int tid  = threadIdx.x;
    const int m0   = blockIdx.x * 128;
    const int n0   = blockIdx.y * 128;
    const int w    = tid >> 6;
    const int lane = tid & 63;
    const int quad = lane >> 4;
    const int ln   = lane & 15;
    const int wm   = (w & 1) * 64;
    const int wn   = (w >> 1) * 64;
    const int lr   = tid >> 1;
    const int lc   = (tid & 1) * 16;

    f32x4 acc[4][4] = {};

    for (int k0 = 0; k0 < DM; k0 += 32) {
        if (A_BF16) {
            const uint4* ap = reinterpret_cast<const uint4*>(
                (const __hip_bfloat16*)Ap + (size_t)(m0 + lr) * DM + k0 + lc);
            uint4 a0 = ap[0], a1 = ap[1];
            *reinterpret_cast<uint4*>(&As[lr][lc])     = a0;
            *reinterpret_cast<uint4*>(&As[lr][lc + 8]) = a1;
        } else {
            const float4* ap = reinterpret_cast<const float4*>(
                (const float*)Ap + (size_t)(m0 + lr) * DM + k0 + lc);
            float4 f0 = ap[0], f1 = ap[1], f2 = ap[2], f3 = ap[3];
            PackB p0, p1;
            p0.h[0] = __float2bfloat16(f0.x); p0.h[1] = __float2bfloat16(f0.y);
            p0.h[2] = __float2bfloat16(f0.z); p0.h[3] = __float2bfloat16(f0.w);
            p0.h[4] = __float2bfloat16(f1.x); p0.h[5] = __float2bfloat16(f1.y);
            p0.h[6] = __float2bfloat16(f1.z); p0.h[7] = __float2bfloat16(f1.w);
            p1.h[0] = __float2bfloat16(f2.x); p1.h[1] = __float2bfloat16(f2.y);
            p1.h[2] = __float2bfloat16(f2.z); p1.h[3] = __float2bfloat16(f2.w);
            p1.h[4] = __float2bfloat16(f3.x); p1.h[5] = __float2bfloat16(f3.y);
            p1.h[6] = __float2bfloat16(f3.z); p1.h[7] = __float2bfloat16(f3.w);
            *reinterpret_cast<uint4*>(&As[lr][lc])     = p0.u;
            *reinterpret_cast<uint4*>(&As[lr][lc + 8]) = p1.u;
        }
        {
            const float4* wp = reinterpret_cast<const float4*>(
                W + (size_t)(n0 + lr) * DM + k0 + lc);
            float4 f0 = wp[0], f1 = wp[1], f2 = wp[2], f3 = wp[3];
            PackB p0, p1;
            p0.h[0] = __float2bfloat16(f0.x); p0.h[1] = __float2bfloat16(f0.y);
            p0.h[2] = __float2bfloat16(f0.z); p0.h[3] = __float2bfloat16(f0.w);
            p0.h[4] = __float2bfloat16(f1.x); p0.h[5] = __float2bfloat16(f1.y);
            p0.h[6] = __float2bfloat16(f1.z); p0.h[7] = __float2bfloat16(f1.w);
            p1.h[0] = __float2bfloat16(f2.x); p1.h[1] = __float2bfloat16(f2.y);
            p1.h[2] = __float2bfloat16(f2.z); p1.h[3] = __float2bfloat16(f2.w);
            p1.h[4] = __float2bfloat16(f3.x); p1.h[5] = __float2bfloat16(f3.y);
            p1.h[6] = __float2bfloat16(f3.z); p1.h[7] = __float2bfloat16(f3.w);
            *reinterpret_cast<uint4*>(&Bs[lr][lc])     = p0.u;
            *reinterpret_cast<uint4*>(&Bs[lr][lc + 8]) = p1.u;
        }
        __syncthreads();

        short8 a[4], b[4];
        #pragma unroll
        for (int i = 0; i < 4; i++)
            a[i] = *reinterpret_cast<const short8*>(&As[wm + i*16 + ln][quad*8]);
        #pragma unroll
        for (int j = 0; j < 4; j++)
            b[j] = *reinterpret_cast<const short8*>(&Bs[wn + j*16 + ln][quad*8]);
        #pragma unroll
        for (int i = 0; i < 4; i++)
            #pragma unroll
            for (int j = 0; j < 4; j++)
                acc[i][j] = __builtin_amdgcn_mfma_f32_16x16x32_bf16(a[i], b[j], acc[i][j], 0, 0, 0);
        __syncthreads();
    }

    #pragma unroll
    for (int i = 0; i < 4; i++) {
        #pragma unroll
        for (int j = 0; j < 4; j++) {
            #pragma unroll
            for (int r = 0; r < 4; r++) {
                const int m = m0 + wm + i*16 + quad*4 + r;
                const int n = n0 + wn + j*16 + ln;
                const float v = acc[i][j][r];
                if (MODE == 2) {
                    ((float*)outp)[(size_t)m * DM + n] = v;
                } else {
                    const int b_ = m >> 11;
                    const int s  = m & 2047;
                    const int h  = n >> 6;
                    const int d  = n & 63;
                    size_t idx;
                    if (MODE == 0) idx = ((size_t)((b_*NH + h)*SL + s))*DK + d;
                    else           idx = ((size_t)((b_*NH + h)*DK + d))*SL + s;
                    ((__hip_bfloat16*)outp)[idx] = __float2bfloat16(v);
                }
            }
        }
    }
}

// ---------------------------------------------------------------------------
// Causal flash attention, LDS-staged K/V tiles (round-7, unchanged).
// ---------------------------------------------------------------------------
__global__ __launch_bounds__(256)
void attn_causal(const __hip_bfloat16* __restrict__ Q,
                 const __hip_bfloat16* __restrict__ K,
                 const __hip_bfloat16* __restrict__ Vt,
                 __hip_bfloat16* __restrict__ O)
{
    __shared__ __hip_bfloat16 Ks[64][72];
    __shared__ __hip_bfloat16 Vs[64][72];
    __shared__ __hip_bfloat16 p_lds[4][16][72];

    const int tid  = threadIdx.x;
    const int w    = tid >> 6;
    const int lane = tid & 63;
    const int quad = lane >> 4;
    const int ln   = lane & 15;
    const int bh   = blockIdx.y;
    const int b_   = bh >> 4;
    const int h    = bh & 15;

    const int srow   = tid >> 3;
    const int schunk = (tid & 7) * 8;

    const __hip_bfloat16* Qb = Q  + (size_t)bh * SL * DK;
    const __hip_bfloat16* Kb = K  + (size_t)bh * SL * DK;
    const __hip_bfloat16* Vb = Vt + (size_t)bh * DK * SL;

    for (int pass = 0; pass < 2; ++pass) {
        const int qt    = (pass == 0) ? (int)blockIdx.x : 31 - (int)blockIdx.x;
        const int q0    = qt * 64;
        const int qbase = q0 + w * 16;

        short8 aq0 = *reinterpret_cast<const short8*>(Qb + (size_t)(qbase + ln) * DK + quad*8);
        short8 aq1 = *reinterpret_cast<const short8*>(Qb + (size_t)(qbase + ln) * DK + 32 + quad*8);

        f32x4 acc[4] = {};
        float lsum[4] = {0.f, 0.f, 0.f, 0.f};

        for (int k0 = 0; k0 <= q0; k0 += 64) {
            const __hip_bfloat16* Kg = Kb + (size_t)(k0 + srow) * DK + schunk;
            uint4 kv0 = *reinterpret_cast<const uint4*>(Kg);
            uint4 kv1 = *reinterpret_cast<const uint4*>(Kg + 32 * DK);
            const __hip_bfloat16* Vg = Vb + (size_t)srow * SL + k0 + schunk;
            uint4 vv0 = *reinterpret_cast<const uint4*>(Vg);
            uint4 vv1 = *reinterpret_cast<const uint4*>(Vg + 32 * SL);
            __syncthreads();
            *reinterpret_cast<uint4*>(&Ks[srow     ][schunk]) = kv0;
            *reinterpret_cast<uint4*>(&Ks[srow + 32][schunk]) = kv1;
            *reinterpret_cast<uint4*>(&Vs[srow     ][schunk]) = vv0;
            *reinterpret_cast<uint4*>(&Vs[srow + 32][schunk]) = vv1;
            __syncthreads();

            f32x4 s[4];
            #pragma unroll
            for (int kc = 0; kc < 4; kc++) {
                short8 bk0 = *reinterpret_cast<const short8*>(&Ks[kc*16 + ln][quad*8]);
                short8 bk1 = *reinterpret_cast<const short8*>(&Ks[kc*16 + ln][32 + quad*8]);
                f32x4 z = {};
                z = __builtin_amdgcn_mfma_f32_16x16x32_bf16(aq0, bk0, z, 0, 0, 0);
                z = __builtin_amdgcn_mfma_f32_16x16x32_bf16(aq1, bk1, z, 0, 0, 0);
                s[kc] = z;
            }
            const bool diag = (k0 == q0);
            #pragma unroll
            for (int kc = 0; kc < 4; kc++) {
                #pragma unroll
                for (int r = 0; r < 4; r++) {
                    float v = s[kc][r] * SC_LOG2E;
                    if (diag) {
                        const int kg = k0 + kc*16 + ln;
                        const int qg = qbase + quad*4 + r;
                        if (kg > qg) v = NEG_BIG;
                    }
                    const float p = __builtin_amdgcn_exp2f(v);
                    lsum[r] += p;
                    p_lds[w][quad*4 + r][kc*16 + ln] = __float2bfloat16(p);
                }
            }
            short8 ap0 = *reinterpret_cast<const short8*>(&p_lds[w][ln][quad*8]);
            short8 ap1 = *reinterpret_cast<const short8*>(&p_lds[w][ln][32 + quad*8]);
            #pragma unroll
            for (int nt = 0; nt < 4; nt++) {
                short8 bv0 = *reinterpret_cast<const short8*>(&Vs[nt*16 + ln][quad*8]);
                short8 bv1 = *reinterpret_cast<const short8*>(&Vs[nt*16 + ln][32 + quad*8]);
                acc[nt] = __builtin_amdgcn_mfma_f32_16x16x32_bf16(ap0, bv0, acc[nt], 0, 0, 0);
                acc[nt] = __builtin_amdgcn_mfma_f32_16x16x32_bf16(ap1, bv1, acc[nt], 0, 0, 0);
            }
        }

        #pragma unroll
        for (int r = 0; r < 4; r++) {
            float v = lsum[r];
            v += __shfl_xor(v, 1, 64);
            v += __shfl_xor(v, 2, 64);
            v += __shfl_xor(v, 4, 64);
            v += __shfl_xor(v, 8, 64);
            lsum[r] = v;
        }

        #pragma unroll
        for (int nt = 0; nt < 4; nt++) {
            #pragma unroll
            for (int r = 0; r < 4; r++) {
                const int sI = qbase + quad*4 + r;
                const int d  = nt*16 + ln;
                const float v = acc[nt][r] / lsum[r];
                O[(((size_t)b_ * SL + sI) * NH + h) * DK + d] = __float2bfloat16(v);
            }
        }
    }
}

// ---------------------------------------------------------------------------
// ws layout (fast path, 72 MiB): [q 16M][k 16M][v 16M][xb 16M][wq 2M][wk 2M]
// [wv 2M][wo 2M]. fp32 final result overlays q+k (dead after attn).
// Fallback (< 72 MiB): round-7 structure (48 MiB).
// ---------------------------------------------------------------------------
extern "C" void kernel_launch(void* const* d_in, const int* in_sizes, int n_in,
                              void* d_out, int out_size, void* d_ws, size_t ws_size,
                              hipStream_t stream)
{
    const float* x  = (const float*)d_in[0];
    const float* Wq = (const float*)d_in[1];
    const float* Wk = (const float*)d_in[2];
    const float* Wv = (const float*)d_in[3];
    const float* Wo = (const float*)d_in[4];

    __hip_bfloat16* q_ws = (__hip_bfloat16*)d_ws;
    __hip_bfloat16* k_ws = q_ws + QKV_ELEMS;
    __hip_bfloat16* v_ws = k_ws + QKV_ELEMS;
    __hip_bfloat16* obuf = (__hip_bfloat16*)d_out;
    float*          fbuf = (float*)d_ws;

    const dim3 gg(64, 8), gb(256);
    const size_t FAST_WS = (3 * QKV_ELEMS + QKV_ELEMS + 4 * (size_t)DM * DM)
                           * sizeof(__hip_bfloat16);   // 72 MiB

    if (ws_size >= FAST_WS) {
        __hip_bfloat16* xb  = v_ws + QKV_ELEMS;
        __hip_bfloat16* wqb = xb  + QKV_ELEMS;
        __hip_bfloat16* wkb = wqb + (size_t)DM * DM;
        __hip_bfloat16* wvb = wkb + (size_t)DM * DM;
        __hip_bfloat16* wob = wvb + (size_t)DM * DM;

        cvt_all<<<12288, 256, 0, stream>>>(x, Wq, Wk, Wv, Wo, xb);

        gemm_lds<0><<<gg, gb, 0, stream>>>(xb, wqb, q_ws);
        gemm_lds<0><<<gg, gb, 0, stream>>>(xb, wkb, k_ws);
        gemm_lds<1><<<gg, gb, 0, stream>>>(xb, wvb, v_ws);

        attn_causal<<<dim3(16, BB*NH), 256, 0, stream>>>(q_ws, k_ws, v_ws, obuf);

        gemm_lds<2><<<gg, gb, 0, stream>>>(obuf, wob, fbuf);
    } else {
        gemm_bt<false, 0><<<gg, gb, 0, stream>>>(x, Wq, q_ws);
        gemm_bt<false, 0><<<gg, gb, 0, stream>>>(x, Wk, k_ws);
        gemm_bt<false, 1><<<gg, gb, 0, stream>>>(x, Wv, v_ws);

        attn_causal<<<dim3(16, BB*NH), 256, 0, stream>>>(q_ws, k_ws, v_ws, obuf);

        gemm_bt<true, 2><<<gg, gb, 0, stream>>>(obuf, Wo, fbuf);
    }

    (void)hipMemcpyAsync(d_out, fbuf, QKV_ELEMS * sizeof(float),
                         hipMemcpyDeviceToDevice, stream);
}

// Round 9
// 284.634 us; speedup vs baseline: 1.8042x; 1.0234x over previous
//
#include <hip/hip_runtime.h>
#include <hip/hip_bf16.h>

typedef __attribute__((ext_vector_type(8))) short short8;
typedef __attribute__((ext_vector_type(4))) float f32x4;

static constexpr int DM = 1024;   // d_model
static constexpr int NH = 16;     // heads
static constexpr int DK = 64;     // head dim
static constexpr int SL = 2048;   // seq len
static constexpr int BB = 4;      // batch
static constexpr size_t QKV_ELEMS = (size_t)BB * NH * SL * DK;  // 8388608
static constexpr float NEG_BIG = -30000.0f;          // exp2 -> 0
static constexpr float SC_LOG2E = 0.125f * 1.44269504088896340736f; // /sqrt(64)*log2(e)

union PackB { __hip_bfloat16 h[8]; uint4 u; };
union Pack4 { __hip_bfloat16 h[4]; uint2 u; };

// async global->LDS, 16 B per lane (dest = wave-uniform base + lane*16)
typedef __attribute__((address_space(1))) unsigned int gu32;
typedef __attribute__((address_space(3))) unsigned int lu32;
__device__ __forceinline__ void async_copy16(const void* g, void* l) {
    __builtin_amdgcn_global_load_lds((gu32*)g, (lu32*)l, 16, 0, 0);
}

// ---------------------------------------------------------------------------
// Bulk fp32 -> bf16 convert: x (8M elems) then Wq,Wk,Wv,Wo (1M each) into one
// contiguous bf16 region. One float4 per thread.
// ---------------------------------------------------------------------------
__global__ __launch_bounds__(256)
void cvt_all(const float* __restrict__ x,
             const float* __restrict__ wq, const float* __restrict__ wk,
             const float* __restrict__ wv, const float* __restrict__ wo,
             __hip_bfloat16* __restrict__ dst)
{
    const size_t i = (size_t)blockIdx.x * 256 + threadIdx.x;  // float4 index
    const float* src; size_t local;
    if (i < 2097152) { src = x; local = i; }
    else {
        const size_t j = i - 2097152;
        const int r = (int)(j >> 18);           // 262144 float4 per W
        local = j & 262143;
        src = (r == 0) ? wq : (r == 1) ? wk : (r == 2) ? wv : wo;
    }
    float4 f = reinterpret_cast<const float4*>(src)[local];
    Pack4 p;
    p.h[0] = __float2bfloat16(f.x); p.h[1] = __float2bfloat16(f.y);
    p.h[2] = __float2bfloat16(f.z); p.h[3] = __float2bfloat16(f.w);
    reinterpret_cast<uint2*>(dst)[i] = p.u;
}

// ---------------------------------------------------------------------------
// Fused QKV projection, m97 structure: A (8192 x 1024 bf16) @ Wqkv^T where
// Wqkv = [Wq;Wk;Wv] (3072 x 1024 bf16, rows contiguous). Grid (64, 24) =
// 1536 blocks -> 6 blocks/CU oversubscription. Scatter: Q,K -> [B,H,S,D],
// V -> [B,H,D,S].
// ---------------------------------------------------------------------------
__global__ __launch_bounds__(256)
void gemm_qkv(const __hip_bfloat16* __restrict__ A,
              const __hip_bfloat16* __restrict__ W,
              __hip_bfloat16* __restrict__ q_out,
              __hip_bfloat16* __restrict__ k_out,
              __hip_bfloat16* __restrict__ v_out)
{
    __shared__ __hip_bfloat16 As[128 * 32];   // contiguous: global_load_lds order
    __shared__ __hip_bfloat16 Bs[128 * 32];
    const int tid  = threadIdx.x;
    const int m0   = blockIdx.x * 128;
    const int n0   = blockIdx.y * 128;
    const int w    = tid >> 6;
    const int lane = tid & 63;
    const int quad = lane >> 4;
    const int ln   = lane & 15;
    const int wm   = (w & 1) * 64;
    const int wn   = (w >> 1) * 64;
    const int srow   = lane >> 2;        // 0..15
    const int schunk = (lane & 3) * 8;   // element offset

    f32x4 acc[4][4] = {};

    for (int k0 = 0; k0 < DM; k0 += 32) {
        #pragma unroll
        for (int j = 0; j < 2; j++) {
            const int rbase = w * 32 + j * 16;
            async_copy16(A + (size_t)(m0 + rbase + srow) * DM + k0 + schunk,
                         &As[rbase * 32]);
            async_copy16(W + (size_t)(n0 + rbase + srow) * DM + k0 + schunk,
                         &Bs[rbase * 32]);
        }
        __syncthreads();

        short8 a[4], b[4];
        #pragma unroll
        for (int i = 0; i < 4; i++)
            a[i] = *reinterpret_cast<const short8*>(&As[(wm + i*16 + ln) * 32 + quad*8]);
        #pragma unroll
        for (int j = 0; j < 4; j++)
            b[j] = *reinterpret_cast<const short8*>(&Bs[(wn + j*16 + ln) * 32 + quad*8]);
        #pragma unroll
        for (int i = 0; i < 4; i++)
            #pragma unroll
            for (int j = 0; j < 4; j++)
                acc[i][j] = __builtin_amdgcn_mfma_f32_16x16x32_bf16(a[i], b[j], acc[i][j], 0, 0, 0);
        __syncthreads();
    }

    // Epilogue: C/D layout col=lane&15, row=quad*4+reg  [m89/m91]
    #pragma unroll
    for (int i = 0; i < 4; i++) {
        #pragma unroll
        for (int j = 0; j < 4; j++) {
            #pragma unroll
            for (int r = 0; r < 4; r++) {
                const int m = m0 + wm + i*16 + quad*4 + r;
                const int n = n0 + wn + j*16 + ln;     // 0..3071
                const int b_ = m >> 11;
                const int s  = m & 2047;
                const int which = n >> 10;             // 0=Q 1=K 2=V
                const int nn = n & 1023;
                const int h  = nn >> 6;
                const int d  = nn & 63;
                const __hip_bfloat16 v = __float2bfloat16(acc[i][j][r]);
                if (which == 0)
                    q_out[((size_t)((b_*NH + h)*SL + s))*DK + d] = v;
                else if (which == 1)
                    k_out[((size_t)((b_*NH + h)*SL + s))*DK + d] = v;
                else
                    v_out[((size_t)((b_*NH + h)*DK + d))*SL + s] = v;
            }
        }
    }
}

// ---------------------------------------------------------------------------
// Pure-bf16 GEMM, m97 structure (final projection): out fp32 row-major.
// ---------------------------------------------------------------------------
__global__ __launch_bounds__(256)
void gemm_wo(const __hip_bfloat16* __restrict__ A,
             const __hip_bfloat16* __restrict__ W,
             float* __restrict__ outp)
{
    __shared__ __hip_bfloat16 As[128 * 32];
    __shared__ __hip_bfloat16 Bs[128 * 32];
    const int tid  = threadIdx.x;
    const int m0   = blockIdx.x * 128;
    const int n0   = blockIdx.y * 128;
    const int w    = tid >> 6;
    const int lane = tid & 63;
    const int quad = lane >> 4;
    const int ln   = lane & 15;
    const int wm   = (w & 1) * 64;
    const int wn   = (w >> 1) * 64;
    const int srow   = lane >> 2;
    const int schunk = (lane & 3) * 8;

    f32x4 acc[4][4] = {};

    for (int k0 = 0; k0 < DM; k0 += 32) {
        #pragma unroll
        for (int j = 0; j < 2; j++) {
            const int rbase = w * 32 + j * 16;
            async_copy16(A + (size_t)(m0 + rbase + srow) * DM + k0 + schunk,
                         &As[rbase * 32]);
            async_copy16(W + (size_t)(n0 + rbase + srow) * DM + k0 + schunk,
                         &Bs[rbase * 32]);
        }
        __syncthreads();

        short8 a[4], b[4];
        #pragma unroll
        for (int i = 0; i < 4; i++)
            a[i] = *reinterpret_cast<const short8*>(&As[(wm + i*16 + ln) * 32 + quad*8]);
        #pragma unroll
        for (int j = 0; j < 4; j++)
            b[j] = *reinterpret_cast<const short8*>(&Bs[(wn + j*16 + ln) * 32 + quad*8]);
        #pragma unroll
        for (int i = 0; i < 4; i++)
            #pragma unroll
            for (int j = 0; j < 4; j++)
                acc[i][j] = __builtin_amdgcn_mfma_f32_16x16x32_bf16(a[i], b[j], acc[i][j], 0, 0, 0);
        __syncthreads();
    }

    #pragma unroll
    for (int i = 0; i < 4; i++)
        #pragma unroll
        for (int j = 0; j < 4; j++)
            #pragma unroll
            for (int r = 0; r < 4; r++) {
                const int m = m0 + wm + i*16 + quad*4 + r;
                const int n = n0 + wn + j*16 + ln;
                outp[(size_t)m * DM + n] = acc[i][j][r];
            }
}

// ---------------------------------------------------------------------------
// Fallback GEMM (round-7 proven): fp32 inputs, convert during staging.
// ---------------------------------------------------------------------------
template<bool A_BF16, int MODE>
__global__ __launch_bounds__(256)
void gemm_bt(const void* __restrict__ Ap,
             const float* __restrict__ W,
             void* __restrict__ outp)
{
    __shared__ __hip_bfloat16 As[128][40];
    __shared__ __hip_bfloat16 Bs[128][40];
    const int tid  = threadIdx.x;
    const int m0   = blockIdx.x * 128;
    const int n0   = blockIdx.y * 128;
    const int w    = tid >> 6;
    const int lane = tid & 63;
    const int quad = lane >> 4;
    const int ln   = lane & 15;
    const int wm   = (w & 1) * 64;
    const int wn   = (w >> 1) * 64;
    const int lr   = tid >> 1;
    const int lc   = (tid & 1) * 16;

    f32x4 acc[4][4] = {};

    for (int k0 = 0; k0 < DM; k0 += 32) {
        if (A_BF16) {
            const uint4* ap = reinterpret_cast<const uint4*>(
                (const __hip_bfloat16*)Ap + (size_t)(m0 + lr) * DM + k0 + lc);
            uint4 a0 = ap[0], a1 = ap[1];
            *reinterpret_cast<uint4*>(&As[lr][lc])     = a0;
            *reinterpret_cast<uint4*>(&As[lr][lc + 8]) = a1;
        } else {
            const float4* ap = reinterpret_cast<const float4*>(
                (const float*)Ap + (size_t)(m0 + lr) * DM + k0 + lc);
            float4 f0 = ap[0], f1 = ap[1], f2 = ap[2], f3 = ap[3];
            PackB p0, p1;
            p0.h[0] = __float2bfloat16(f0.x); p0.h[1] = __float2bfloat16(f0.y);
            p0.h[2] = __float2bfloat16(f0.z); p0.h[3] = __float2bfloat16(f0.w);
            p0.h[4] = __float2bfloat16(f1.x); p0.h[5] = __float2bfloat16(f1.y);
            p0.h[6] = __float2bfloat16(f1.z); p0.h[7] = __float2bfloat16(f1.w);
            p1.h[0] = __float2bfloat16(f2.x); p1.h[1] = __float2bfloat16(f2.y);
            p1.h[2] = __float2bfloat16(f2.z); p1.h[3] = __float2bfloat16(f2.w);
            p1.h[4] = __float2bfloat16(f3.x); p1.h[5] = __float2bfloat16(f3.y);
            p1.h[6] = __float2bfloat16(f3.z); p1.h[7] = __float2bfloat16(f3.w);
            *reinterpret_cast<uint4*>(&As[lr][lc])     = p0.u;
            *reinterpret_cast<uint4*>(&As[lr][lc + 8]) = p1.u;
        }
        {
            const float4* wp = reinterpret_cast<const float4*>(
                W + (size_t)(n0 + lr) * DM + k0 + lc);
            float4 f0 = wp[0], f1 = wp[1], f2 = wp[2], f3 = wp[3];
            PackB p0, p1;
            p0.h[0] = __float2bfloat16(f0.x); p0.h[1] = __float2bfloat16(f0.y);
            p0.h[2] = __float2bfloat16(f0.z); p0.h[3] = __float2bfloat16(f0.w);
            p0.h[4] = __float2bfloat16(f1.x); p0.h[5] = __float2bfloat16(f1.y);
            p0.h[6] = __float2bfloat16(f1.z); p0.h[7] = __float2bfloat16(f1.w);
            p1.h[0] = __float2bfloat16(f2.x); p1.h[1] = __float2bfloat16(f2.y);
            p1.h[2] = __float2bfloat16(f2.z); p1.h[3] = __float2bfloat16(f2.w);
            p1.h[4] = __float2bfloat16(f3.x); p1.h[5] = __float2bfloat16(f3.y);
            p1.h[6] = __float2bfloat16(f3.z); p1.h[7] = __float2bfloat16(f3.w);
            *reinterpret_cast<uint4*>(&Bs[lr][lc])     = p0.u;
            *reinterpret_cast<uint4*>(&Bs[lr][lc + 8]) = p1.u;
        }
        __syncthreads();

        short8 a[4], b[4];
        #pragma unroll
        for (int i = 0; i < 4; i++)
            a[i] = *reinterpret_cast<const short8*>(&As[wm + i*16 + ln][quad*8]);
        #pragma unroll
        for (int j = 0; j < 4; j++)
            b[j] = *reinterpret_cast<const short8*>(&Bs[wn + j*16 + ln][quad*8]);
        #pragma unroll
        for (int i = 0; i < 4; i++)
            #pragma unroll
            for (int j = 0; j < 4; j++)
                acc[i][j] = __builtin_amdgcn_mfma_f32_16x16x32_bf16(a[i], b[j], acc[i][j], 0, 0, 0);
        __syncthreads();
    }

    #pragma unroll
    for (int i = 0; i < 4; i++) {
        #pragma unroll
        for (int j = 0; j < 4; j++) {
            #pragma unroll
            for (int r = 0; r < 4; r++) {
                const int m = m0 + wm + i*16 + quad*4 + r;
                const int n = n0 + wn + j*16 + ln;
                const float v = acc[i][j][r];
                if (MODE == 2) {
                    ((float*)outp)[(size_t)m * DM + n] = v;
                } else {
                    const int b_ = m >> 11;
                    const int s  = m & 2047;
                    const int h  = n >> 6;
                    const int d  = n & 63;
                    size_t idx;
                    if (MODE == 0) idx = ((size_t)((b_*NH + h)*SL + s))*DK + d;
                    else           idx = ((size_t)((b_*NH + h)*DK + d))*SL + s;
                    ((__hip_bfloat16*)outp)[idx] = __float2bfloat16(v);
                }
            }
        }
    }
}

// ---------------------------------------------------------------------------
// Causal flash attention, LDS-staged K/V tiles (round-7, unchanged).
// ---------------------------------------------------------------------------
__global__ __launch_bounds__(256)
void attn_causal(const __hip_bfloat16* __restrict__ Q,
                 const __hip_bfloat16* __restrict__ K,
                 const __hip_bfloat16* __restrict__ Vt,
                 __hip_bfloat16* __restrict__ O)
{
    __shared__ __hip_bfloat16 Ks[64][72];
    __shared__ __hip_bfloat16 Vs[64][72];
    __shared__ __hip_bfloat16 p_lds[4][16][72];

    const int tid  = threadIdx.x;
    const int w    = tid >> 6;
    const int lane = tid & 63;
    const int quad = lane >> 4;
    const int ln   = lane & 15;
    const int bh   = blockIdx.y;
    const int b_   = bh >> 4;
    const int h    = bh & 15;

    const int srow   = tid >> 3;
    const int schunk = (tid & 7) * 8;

    const __hip_bfloat16* Qb = Q  + (size_t)bh * SL * DK;
    const __hip_bfloat16* Kb = K  + (size_t)bh * SL * DK;
    const __hip_bfloat16* Vb = Vt + (size_t)bh * DK * SL;

    for (int pass = 0; pass < 2; ++pass) {
        const int qt    = (pass == 0) ? (int)blockIdx.x : 31 - (int)blockIdx.x;
        const int q0    = qt * 64;
        const int qbase = q0 + w * 16;

        short8 aq0 = *reinterpret_cast<const short8*>(Qb + (size_t)(qbase + ln) * DK + quad*8);
        short8 aq1 = *reinterpret_cast<const short8*>(Qb + (size_t)(qbase + ln) * DK + 32 + quad*8);

        f32x4 acc[4] = {};
        float lsum[4] = {0.f, 0.f, 0.f, 0.f};

        for (int k0 = 0; k0 <= q0; k0 += 64) {
            const __hip_bfloat16* Kg = Kb + (size_t)(k0 + srow) * DK + schunk;
            uint4 kv0 = *reinterpret_cast<const uint4*>(Kg);
            uint4 kv1 = *reinterpret_cast<const uint4*>(Kg + 32 * DK);
            const __hip_bfloat16* Vg = Vb + (size_t)srow * SL + k0 + schunk;
            uint4 vv0 = *reinterpret_cast<const uint4*>(Vg);
            uint4 vv1 = *reinterpret_cast<const uint4*>(Vg + 32 * SL);
            __syncthreads();
            *reinterpret_cast<uint4*>(&Ks[srow     ][schunk]) = kv0;
            *reinterpret_cast<uint4*>(&Ks[srow + 32][schunk]) = kv1;
            *reinterpret_cast<uint4*>(&Vs[srow     ][schunk]) = vv0;
            *reinterpret_cast<uint4*>(&Vs[srow + 32][schunk]) = vv1;
            __syncthreads();

            f32x4 s[4];
            #pragma unroll
            for (int kc = 0; kc < 4; kc++) {
                short8 bk0 = *reinterpret_cast<const short8*>(&Ks[kc*16 + ln][quad*8]);
                short8 bk1 = *reinterpret_cast<const short8*>(&Ks[kc*16 + ln][32 + quad*8]);
                f32x4 z = {};
                z = __builtin_amdgcn_mfma_f32_16x16x32_bf16(aq0, bk0, z, 0, 0, 0);
                z = __builtin_amdgcn_mfma_f32_16x16x32_bf16(aq1, bk1, z, 0, 0, 0);
                s[kc] = z;
            }
            const bool diag = (k0 == q0);
            #pragma unroll
            for (int kc = 0; kc < 4; kc++) {
                #pragma unroll
                for (int r = 0; r < 4; r++) {
                    float v = s[kc][r] * SC_LOG2E;
                    if (diag) {
                        const int kg = k0 + kc*16 + ln;
                        const int qg = qbase + quad*4 + r;
                        if (kg > qg) v = NEG_BIG;
                    }
                    const float p = __builtin_amdgcn_exp2f(v);
                    lsum[r] += p;
                    p_lds[w][quad*4 + r][kc*16 + ln] = __float2bfloat16(p);
                }
            }
            short8 ap0 = *reinterpret_cast<const short8*>(&p_lds[w][ln][quad*8]);
            short8 ap1 = *reinterpret_cast<const short8*>(&p_lds[w][ln][32 + quad*8]);
            #pragma unroll
            for (int nt = 0; nt < 4; nt++) {
                short8 bv0 = *reinterpret_cast<const short8*>(&Vs[nt*16 + ln][quad*8]);
                short8 bv1 = *reinterpret_cast<const short8*>(&Vs[nt*16 + ln][32 + quad*8]);
                acc[nt] = __builtin_amdgcn_mfma_f32_16x16x32_bf16(ap0, bv0, acc[nt], 0, 0, 0);
                acc[nt] = __builtin_amdgcn_mfma_f32_16x16x32_bf16(ap1, bv1, acc[nt], 0, 0, 0);
            }
        }

        #pragma unroll
        for (int r = 0; r < 4; r++) {
            float v = lsum[r];
            v += __shfl_xor(v, 1, 64);
            v += __shfl_xor(v, 2, 64);
            v += __shfl_xor(v, 4, 64);
            v += __shfl_xor(v, 8, 64);
            lsum[r] = v;
        }

        #pragma unroll
        for (int nt = 0; nt < 4; nt++) {
            #pragma unroll
            for (int r = 0; r < 4; r++) {
                const int sI = qbase + quad*4 + r;
                const int d  = nt*16 + ln;
                const float v = acc[nt][r] / lsum[r];
                O[(((size_t)b_ * SL + sI) * NH + h) * DK + d] = __float2bfloat16(v);
            }
        }
    }
}

// ---------------------------------------------------------------------------
// ws layout (fast path, 72 MiB): [q 16M][k 16M][v 16M][xb 16M][wq 2M][wk 2M]
// [wv 2M][wo 2M]. Attention O reuses xb (dead after projections); Wo GEMM
// writes fp32 directly to d_out (no copy).
// ---------------------------------------------------------------------------
extern "C" void kernel_launch(void* const* d_in, const int* in_sizes, int n_in,
                              void* d_out, int out_size, void* d_ws, size_t ws_size,
                              hipStream_t stream)
{
    const float* x  = (const float*)d_in[0];
    const float* Wq = (const float*)d_in[1];
    const float* Wk = (const float*)d_in[2];
    const float* Wv = (const float*)d_in[3];
    const float* Wo = (const float*)d_in[4];

    __hip_bfloat16* q_ws = (__hip_bfloat16*)d_ws;
    __hip_bfloat16* k_ws = q_ws + QKV_ELEMS;
    __hip_bfloat16* v_ws = k_ws + QKV_ELEMS;

    const dim3 gb(256);
    const size_t FAST_WS = (3 * QKV_ELEMS + QKV_ELEMS + 4 * (size_t)DM * DM)
                           * sizeof(__hip_bfloat16);   // 72 MiB

    if (ws_size >= FAST_WS) {
        __hip_bfloat16* xb  = v_ws + QKV_ELEMS;
        __hip_bfloat16* wqb = xb  + QKV_ELEMS;        // [Wq;Wk;Wv] contiguous
        __hip_bfloat16* wob = wqb + 3 * (size_t)DM * DM;

        cvt_all<<<12288, 256, 0, stream>>>(x, Wq, Wk, Wv, Wo, xb);

        gemm_qkv<<<dim3(64, 24), gb, 0, stream>>>(xb, wqb, q_ws, k_ws, v_ws);

        attn_causal<<<dim3(16, BB*NH), 256, 0, stream>>>(q_ws, k_ws, v_ws, xb);

        gemm_wo<<<dim3(64, 8), gb, 0, stream>>>(xb, wob, (float*)d_out);
    } else {
        __hip_bfloat16* obuf = (__hip_bfloat16*)d_out;
        float*          fbuf = (float*)d_ws;
        const dim3 gg(64, 8);
        gemm_bt<false, 0><<<gg, gb, 0, stream>>>(x, Wq, q_ws);
        gemm_bt<false, 0><<<gg, gb, 0, stream>>>(x, Wk, k_ws);
        gemm_bt<false, 1><<<gg, gb, 0, stream>>>(x, Wv, v_ws);
        attn_causal<<<dim3(16, BB*NH), 256, 0, stream>>>(q_ws, k_ws, v_ws, obuf);
        gemm_bt<true, 2><<<gg, gb, 0, stream>>>(obuf, Wo, fbuf);
        (void)hipMemcpyAsync(d_out, fbuf, QKV_ELEMS * sizeof(float),
                             hipMemcpyDeviceToDevice, stream);
    }
}